// Round 9
// baseline (195.522 us; speedup 1.0000x reference)
//
#include <hip/hip_runtime.h>
#include <math.h>

// Problem constants
#define B_   8
#define C_   64
#define O_   64
#define H_   128
#define W_   128
#define HW_  (H_ * W_)
#define KSZ  576            // C_*9 contraction length

typedef _Float16 f16x8 __attribute__((ext_vector_type(8)));
typedef float    f32x4 __attribute__((ext_vector_type(4)));

#define WPM_BYTES (18 * 4 * 64 * 8 * 2)   // 73728
#define WPA_BYTES (18 * 2 * 64 * 8 * 2)   // 36864
#define TB_       (B_ * HW_ / 64)         // 2048 transpose tiles (64 px x 64 ch)

// ---------------------------------------------------------------------------
// Prep kernel (unchanged from r8).
// Blocks [0,TB_): LDS-tiled transpose x (B,C,H,W) fp32 -> (B,H,W,C) f16.
// Blocks [TB_, TB_+27): prepack weights into f16 MFMA A-fragment layout.
//   A-frag element (chunk s, m-tile mt, lane, j):
//   row = mt*16+(lane&15), k-local = (lane>>4)*8+j; tap k=s>>1, cbase=(s&1)*32.
// ---------------------------------------------------------------------------
__global__ __launch_bounds__(256) void prep_kernel(
    const float* __restrict__ x,
    const float* __restrict__ offw, const float* __restrict__ modw,
    const float* __restrict__ wgt,
    _Float16* __restrict__ xT, _Float16* __restrict__ wpM, _Float16* __restrict__ wpA)
{
    const int bi = blockIdx.x;
    if (bi < TB_) {
        __shared__ _Float16 tile[64 * 68];
        const int tid = threadIdx.x;
        const int b      = bi >> 8;
        const int pxbase = (bi & 255) * 64;

        const int px = tid & 63;
        const int cr = (tid >> 6) * 16;
        const float* __restrict__ xp = x + (size_t)b * C_ * HW_ + pxbase + px;
#pragma unroll
        for (int r = 0; r < 16; ++r) {
            const int c = cr + r;
            tile[px * 68 + c] = (_Float16)xp[(size_t)c * HW_];
        }
        __syncthreads();

        const int px2 = tid >> 2;
        const int c0  = (tid & 3) * 16;
        f16x8 v0, v1;
#pragma unroll
        for (int j = 0; j < 8; ++j) {
            v0[j] = tile[px2 * 68 + c0 + j];
            v1[j] = tile[px2 * 68 + c0 + 8 + j];
        }
        _Float16* __restrict__ op = xT + ((size_t)b * HW_ + pxbase + px2) * 64 + c0;
        *(f16x8*)&op[0] = v0;
        *(f16x8*)&op[8] = v1;
        return;
    }
    const int g = (bi - TB_) * 256 + threadIdx.x;
    if (g < 18 * 4 * 64) {
        const int s = g >> 8, mt = (g >> 6) & 3, lane = g & 63;
        const int k = s >> 1, cb = (s & 1) * 32;
        const int o  = mt * 16 + (lane & 15);
        const int c0 = cb + (lane >> 4) * 8;
        f16x8 v;
#pragma unroll
        for (int j = 0; j < 8; ++j) v[j] = (_Float16)wgt[o * KSZ + (c0 + j) * 9 + k];
        *(f16x8*)&wpM[(size_t)g * 8] = v;
    } else if (g < 18 * 4 * 64 + 18 * 2 * 64) {
        const int u = g - 18 * 4 * 64;
        const int s = u >> 7, mt = (u >> 6) & 1, lane = u & 63;
        const int k = s >> 1, cb = (s & 1) * 32;
        const int t  = mt * 16 + (lane & 15);
        const int c0 = cb + (lane >> 4) * 8;
        f16x8 v;
#pragma unroll
        for (int j = 0; j < 8; ++j) {
            float w = 0.0f;
            if (t < 18)      w = offw[t * KSZ + (c0 + j) * 9 + k];
            else if (t < 27) w = modw[(t - 18) * KSZ + (c0 + j) * 9 + k];
            v[j] = (_Float16)w;
        }
        *(f16x8*)&wpA[(size_t)u * 8] = v;
    }
}

__device__ __forceinline__ f16x8 splat8(_Float16 h) {
    f16x8 v = {h, h, h, h, h, h, h, h};
    return v;
}

// ---------------------------------------------------------------------------
// Fused main kernel, tap-deduplicated. Block = 256 thr (4 waves); each wave
// owns 16 px (1 N-tile). Grid = B*H*2 = 2048 blocks.
// Phase B loops over taps k=0..8: ONE bilinear setup per tap, then all 8
// corner loads (both channel-halves) issued back-to-back (one vmcnt group),
// then 2 combines + 2x4 MFMAs. Keeps VGPR ~<=128 for 4 waves/SIMD.
// ---------------------------------------------------------------------------
__global__ __launch_bounds__(256) void dcn_main_kernel(
    const _Float16* __restrict__ xT,    // (B, H, W, C) f16
    const _Float16* __restrict__ wpA,   // packed offset/mod weight frags
    const _Float16* __restrict__ wpM,   // packed main weight frags
    const float* __restrict__ offb,     // (18,)
    const float* __restrict__ modb,     // (9,)
    float* __restrict__ out)            // (B, O, H, W)
{
    __shared__ float params[4][27][16];   // [wave][t][px-in-wave-tile]

    const int tid  = threadIdx.x;
    const int lane = tid & 63;
    const int wave = tid >> 6;
    const int lq   = lane >> 4;
    const int ln   = lane & 15;

    const int bi   = blockIdx.x;
    const int b    = bi & 7;             // XCD-pinned batch
    const int rest = bi >> 3;
    const int ho   = rest >> 1;
    const int xh   = rest & 1;
    const int wo   = xh * 64 + wave * 16 + ln;   // this lane's pixel column

    const _Float16* __restrict__ xbT = xT + (size_t)b * HW_ * 64;

    // ---------------- Phase A: offset/modulator conv via MFMA ----------------
    f32x4 accA[2];
    accA[0] = (f32x4){0.f, 0.f, 0.f, 0.f};
    accA[1] = (f32x4){0.f, 0.f, 0.f, 0.f};

#pragma unroll
    for (int k = 0; k < 9; ++k) {
        const int ki = k / 3, kj = k - ki * 3;
        const int y  = ho - 1 + ki;
        const int xx = wo - 1 + kj;
        const bool v = (y >= 0) && (y < H_) && (xx >= 0) && (xx < W_);
        const _Float16* __restrict__ pv = &xbT[((size_t)(y * W_ + xx)) * 64 + lq * 8];
        f16x8 bfA0, bfA1;
        if (v) {
            bfA0 = *(const f16x8*)&pv[0];
            bfA1 = *(const f16x8*)&pv[32];
        } else {
            bfA0 = splat8((_Float16)0.0f);
            bfA1 = splat8((_Float16)0.0f);
        }
        f16x8 afA0[2], afA1[2];
#pragma unroll
        for (int mt = 0; mt < 2; ++mt) {
            afA0[mt] = *(const f16x8*)&wpA[(size_t)(((2 * k)     * 2 + mt) * 64 + lane) * 8];
            afA1[mt] = *(const f16x8*)&wpA[(size_t)(((2 * k + 1) * 2 + mt) * 64 + lane) * 8];
        }
#pragma unroll
        for (int mt = 0; mt < 2; ++mt)
            accA[mt] = __builtin_amdgcn_mfma_f32_16x16x32_f16(afA0[mt], bfA0, accA[mt], 0, 0, 0);
#pragma unroll
        for (int mt = 0; mt < 2; ++mt)
            accA[mt] = __builtin_amdgcn_mfma_f32_16x16x32_f16(afA1[mt], bfA1, accA[mt], 0, 0, 0);
    }

    // Epilogue A: D col = ln (px), row = mt*16 + lq*4 + r = param t.
#pragma unroll
    for (int mt = 0; mt < 2; ++mt)
#pragma unroll
        for (int r = 0; r < 4; ++r) {
            const int t = mt * 16 + lq * 4 + r;
            const float val = accA[mt][r];
            if (t < 18)      params[wave][t][ln] = val + offb[t];
            else if (t < 27) params[wave][t][ln] = 2.0f / (1.0f + expf(-(val + modb[t - 18])));
        }
    __syncthreads();

    // ---------------- Phase B: deformable gather + MFMA, per-tap ----------------
    f32x4 acc[4];
#pragma unroll
    for (int mt = 0; mt < 4; ++mt) acc[mt] = (f32x4){0.f, 0.f, 0.f, 0.f};

#pragma unroll
    for (int k = 0; k < 9; ++k) {
        const int ki = k / 3, kj = k - ki * 3;

        // --- setup ONCE per tap ---
        const float dy = params[wave][2 * k][ln];
        const float dx = params[wave][2 * k + 1][ln];
        const float mk = params[wave][18 + k][ln];

        const float ys = (float)(ho - 1 + ki) + dy;
        const float xs = (float)(wo - 1 + kj) + dx;
        const float y0f = floorf(ys), x0f = floorf(xs);
        const float wy = ys - y0f, wx = xs - x0f;
        const int y0 = (int)y0f, x0 = (int)x0f;
        const int y1 = y0 + 1,  x1 = x0 + 1;
        const bool vy0 = (y0 >= 0) && (y0 < H_);
        const bool vy1 = (y1 >= 0) && (y1 < H_);
        const bool vx0 = (x0 >= 0) && (x0 < W_);
        const bool vx1 = (x1 >= 0) && (x1 < W_);
        const int yc0 = min(max(y0, 0), H_ - 1);
        const int yc1 = min(max(y1, 0), H_ - 1);
        const int xc0 = min(max(x0, 0), W_ - 1);
        const int xc1 = min(max(x1, 0), W_ - 1);
        float w00 = (1.0f - wy) * (1.0f - wx) * mk; if (!(vy0 && vx0)) w00 = 0.0f;
        float w01 = (1.0f - wy) * wx          * mk; if (!(vy0 && vx1)) w01 = 0.0f;
        float w10 = wy          * (1.0f - wx) * mk; if (!(vy1 && vx0)) w10 = 0.0f;
        float w11 = wy          * wx          * mk; if (!(vy1 && vx1)) w11 = 0.0f;

        const int i00 = yc0 * W_ + xc0;
        const int i01 = yc0 * W_ + xc1;
        const int i10 = yc1 * W_ + xc0;
        const int i11 = yc1 * W_ + xc1;

        // --- 8 corner loads (both channel halves) batched ---
        const int ca = lq * 8;           // chunk 0 channels
        const int cbh = 32 + lq * 8;     // chunk 1 channels
        const f16x8 a00 = *(const f16x8*)&xbT[(size_t)i00 * 64 + ca];
        const f16x8 a01 = *(const f16x8*)&xbT[(size_t)i01 * 64 + ca];
        const f16x8 a10 = *(const f16x8*)&xbT[(size_t)i10 * 64 + ca];
        const f16x8 a11 = *(const f16x8*)&xbT[(size_t)i11 * 64 + ca];
        const f16x8 b00 = *(const f16x8*)&xbT[(size_t)i00 * 64 + cbh];
        const f16x8 b01 = *(const f16x8*)&xbT[(size_t)i01 * 64 + cbh];
        const f16x8 b10 = *(const f16x8*)&xbT[(size_t)i10 * 64 + cbh];
        const f16x8 b11 = *(const f16x8*)&xbT[(size_t)i11 * 64 + cbh];

        const f16x8 w00v = splat8((_Float16)w00);
        const f16x8 w01v = splat8((_Float16)w01);
        const f16x8 w10v = splat8((_Float16)w10);
        const f16x8 w11v = splat8((_Float16)w11);

        f16x8 bf0 = a00 * w00v;
        bf0 = a01 * w01v + bf0;
        bf0 = a10 * w10v + bf0;
        bf0 = a11 * w11v + bf0;
        f16x8 bf1 = b00 * w00v;
        bf1 = b01 * w01v + bf1;
        bf1 = b10 * w10v + bf1;
        bf1 = b11 * w11v + bf1;

        // --- chunk 0 MFMAs (s = 2k) ---
        {
            f16x8 af[4];
#pragma unroll
            for (int mt = 0; mt < 4; ++mt)
                af[mt] = *(const f16x8*)&wpM[(size_t)(((2 * k) * 4 + mt) * 64 + lane) * 8];
#pragma unroll
            for (int mt = 0; mt < 4; ++mt)
                acc[mt] = __builtin_amdgcn_mfma_f32_16x16x32_f16(af[mt], bf0, acc[mt], 0, 0, 0);
        }
        // --- chunk 1 MFMAs (s = 2k+1) ---
        {
            f16x8 af[4];
#pragma unroll
            for (int mt = 0; mt < 4; ++mt)
                af[mt] = *(const f16x8*)&wpM[(size_t)(((2 * k + 1) * 4 + mt) * 64 + lane) * 8];
#pragma unroll
            for (int mt = 0; mt < 4; ++mt)
                acc[mt] = __builtin_amdgcn_mfma_f32_16x16x32_f16(af[mt], bf1, acc[mt], 0, 0, 0);
        }
    }

    // Epilogue B: D col = ln -> px = wo, row = o.
    float* __restrict__ ob = out + (size_t)b * O_ * HW_ + (size_t)ho * W_ + wo;
#pragma unroll
    for (int mt = 0; mt < 4; ++mt)
#pragma unroll
        for (int r = 0; r < 4; ++r) {
            const int o = mt * 16 + lq * 4 + r;
            ob[(size_t)o * HW_] = acc[mt][r];
        }
}

extern "C" void kernel_launch(void* const* d_in, const int* in_sizes, int n_in,
                              void* d_out, int out_size, void* d_ws, size_t ws_size,
                              hipStream_t stream) {
    (void)in_sizes; (void)n_in; (void)out_size; (void)ws_size;
    const float* x    = (const float*)d_in[0];
    const float* offw = (const float*)d_in[1];
    const float* offb = (const float*)d_in[2];
    const float* modw = (const float*)d_in[3];
    const float* modb = (const float*)d_in[4];
    const float* wgt  = (const float*)d_in[5];
    float* out = (float*)d_out;

    _Float16* wpM = (_Float16*)d_ws;                                   // 73728 B
    _Float16* wpA = (_Float16*)((char*)d_ws + WPM_BYTES);              // 36864 B
    _Float16* xT  = (_Float16*)((char*)d_ws + WPM_BYTES + WPA_BYTES);  // 16.78 MB

    prep_kernel<<<TB_ + 27, 256, 0, stream>>>(x, offw, modw, wgt, xT, wpM, wpA);
    dcn_main_kernel<<<B_ * H_ * 2, 256, 0, stream>>>(xT, wpA, wpM, offb, modb, out);
}